// Round 16
// baseline (1148.029 us; speedup 1.0000x reference)
//
#include <hip/hip_runtime.h>
#include <math.h>

// ResBlock via bf16 MFMA implicit-GEMM conv3x3.
// R16 = R15 big-tile structure with the two R15 risk items removed:
//  - intrinsic MFMA (asm MFMA was invisible to the hazard recognizer;
//    compiler now handles accvgpr hazards and may still use AGPRs - m97
//    precedent grants 164 VGPR + 64 AGPR with intrinsics)
//  - x_pad back to aliasing d_out; conv<1> residual from fp32 x (R13-proven)
// Block 512thr/8 waves = 256co x (6x48)px; wave = 64co x 144px, acc[4][9].
// Full 256-co per block: x-halo read ONCE. Grid 512 = 2 exact rounds,
// 1 block/CU (96KB LDS), amdgpu_waves_per_eu(2,2) -> 256-reg budget.
// B=16, C=256, H=W=96. Padded channels-last bf16 intermediates [16][98][98][256].

#define Bn 16
#define Cn 256
#define Hn 96
#define Wn 96
#define PH 98
#define PW 98
#define HW (Hn*Wn)

typedef __bf16 bf16x8 __attribute__((ext_vector_type(8)));
typedef float  f32x4  __attribute__((ext_vector_type(4)));

__device__ __forceinline__ unsigned short f2bf(float f) {
    unsigned int u = __float_as_uint(f);
    unsigned int r = (u + 0x7fffu + ((u >> 16) & 1u)) >> 16;
    return (unsigned short)r;
}

__device__ __forceinline__ void lds_load16(void* lds, const void* g) {
    auto gp = (const __attribute__((address_space(1))) char*)(unsigned long long)(uintptr_t)g;
    auto lp = (__attribute__((address_space(3))) char*)(unsigned int)(uintptr_t)lds;
    __builtin_amdgcn_global_load_lds(gp, lp, 16, 0, 0);
}

#define SB() __builtin_amdgcn_sched_barrier(0)
#define MEMFENCE() asm volatile("" ::: "memory")

// ---- zero the padded border of a CL tensor ----
__global__ __launch_bounds__(256)
void zero_border_k(unsigned short* __restrict__ t) {
    int idx = blockIdx.x * 256 + threadIdx.x;      // 16*388*32 threads
    int oct = idx & 31;
    int rest = idx >> 5;
    int pidx = rest % 388;
    int b = rest / 388;
    int h, w;
    if (pidx < 98)       { h = 0;  w = pidx; }
    else if (pidx < 196) { h = 97; w = pidx - 98; }
    else if (pidx < 292) { h = pidx - 196 + 1; w = 0; }
    else                 { h = pidx - 292 + 1; w = 97; }
    size_t e = ((size_t)(b * PH + h) * PW + w) * 256 + oct * 8;
    *(uint4*)(t + e) = make_uint4(0u, 0u, 0u, 0u);
}

// ---- pack weights fp32 [co][ci][3][3] -> bf16 [cc][k9][c'][ci32] ----
template<bool PERM>
__global__ __launch_bounds__(256)
void pack_w_k(const float* __restrict__ w, unsigned short* __restrict__ wp) {
    int idx = blockIdx.x * 256 + threadIdx.x;      // 589824
    int ci_l = idx & 31;
    int c    = (idx >> 5) & 255;
    int v    = idx >> 13;          // 0..71
    int k9   = v % 9;
    int cc   = v / 9;
    int co;
    if (PERM) {
        co = (c < 86) ? c * 3 : (c < 171) ? (c - 86) * 3 + 1 : (c - 171) * 3 + 2;
    } else {
        co = c;
    }
    float val = w[((size_t)co * 256 + cc * 32 + ci_l) * 9 + k9];
    wp[idx] = f2bf(val);
}

// ---- x fp32 NCHW -> padded channels-last bf16 (interior only) ----
__global__ __launch_bounds__(256)
void transform_x_k(const float* __restrict__ x, unsigned short* __restrict__ xp) {
    __shared__ float s[32 * 33];
    const int t = threadIdx.x;
    const int col0 = blockIdx.x * 32;
    const int row  = blockIdx.y;
    const int z = blockIdx.z;
    const int b = z >> 3;
    const int ci0 = (z & 7) * 32;

    #pragma unroll
    for (int i = 0; i < 4; ++i) {
        int ci = i * 8 + (t >> 5);
        int px = t & 31;
        s[ci * 33 + px] = x[((size_t)(b * Cn + ci0 + ci)) * HW + row * Wn + col0 + px];
    }
    __syncthreads();
    const int px = t >> 3;
    const int c4 = (t & 7) * 4;
    ushort4 o;
    o.x = f2bf(s[(c4 + 0) * 33 + px]);
    o.y = f2bf(s[(c4 + 1) * 33 + px]);
    o.z = f2bf(s[(c4 + 2) * 33 + px]);
    o.w = f2bf(s[(c4 + 3) * 33 + px]);
    size_t e = ((size_t)(b * PH + row + 1) * PW + (col0 + px + 1)) * 256 + ci0 + c4;
    *(ushort4*)(xp + e) = o;
}

// ---- Big-tile MFMA conv3x3 ----
// 512 threads (8 waves). Block: 256 co x (6 rows x 48 cols = 288 px).
// Wave wv: co-group g=wv&3 (64 co: m=4 frags), px-half h=wv>>2 (9 n-frags;
// frag hr = h*9+n -> halo row hr/3, col-third hr%3).
// 72 steps s=(c*9+k9). Per step: stage A(s+1) 2 gl_lds + B(c+1) slice
// (k9 in 4..7); 4 A + 9 B ds_read_b128; BAR; lgkm(0); 36 MFMA;
// vmcnt(0) (all loads issued >= one full compute phase earlier); BAR.
// Staging via global_load_lds, PRE-SWIZZLED SOURCE (rule #21), involution
// phys16Bslot = logical ^ ((logical>>3)&3); reads apply the same XOR.
// MODE 0: out = a_cl (bf16 CL, concat-order channels). MODE 1: out = fp32
// NCHW conv*0.1 + fp32 x residual.
template<int MODE>
__global__ __launch_bounds__(512) __attribute__((amdgpu_waves_per_eu(2, 2)))
void conv_k(const unsigned short* __restrict__ in_cl,
            const unsigned short* __restrict__ wp,
            const float* __restrict__ prelu_w,
            const float* __restrict__ xres,
            void* __restrict__ outp)
{
    __shared__ unsigned short s_a[2][1024 * 8];   // 2 x 16KB  [co256][ci32] slice
    __shared__ unsigned short s_b[2][2048 * 8];   // 2 x 32KB  [px(8x50)][ci32] (+junk)

    const int tid = threadIdx.x;
    const int bid = blockIdx.x;
    // XCD-chunked bijective swizzle (512 = 8 * 64).
    const int wg = (bid & 7) * 64 + (bid >> 3);
    const int tile = wg % 32;
    const int b = wg / 32;
    const int tr = tile >> 1;          // 0..15
    const int tc = tile & 1;           // 0..1
    const int R0 = tr * 6;             // halo base row (padded coords)
    const int C0 = tc * 48;

    const int lane = tid & 63;
    const int wv = tid >> 6;
    const int l15 = lane & 15;
    const int qq = lane >> 4;
    const int g  = wv & 3;             // co-group (64 co)
    const int h  = wv >> 2;            // px half (9 frags)
    const int qa = qq ^ ((l15 >> 1) & 3);

    const unsigned short* img = in_cl + (size_t)b * PH * PW * 256;

    // ---- staging maps (gl_lds dest linear; source pre-swizzled) ----
    // B: halo 8x50 = 400 px * 4 parts = 1600 logical slots; 4 slices of 512
    // (dests 1600..2047 are junk, source clamped).
    int bxg[4];
    #pragma unroll
    for (int i = 0; i < 4; ++i) {
        int slot = i * 512 + tid;
        int lsl = slot ^ ((slot >> 3) & 3);    // involution, preserves slot>>3
        if (lsl > 1599) lsl = 1599;
        int p = lsl >> 2;
        int pr = p / 50, pc = p - pr * 50;
        bxg[i] = ((R0 + pr) * PW + (C0 + pc)) * 256 + (lsl & 3) * 8;
    }
    // A: 256co*4 = 1024 slots; 2 per thread
    int axg[2];
    #pragma unroll
    for (int i = 0; i < 2; ++i) {
        int slot = i * 512 + tid;
        int lsl = slot ^ ((slot >> 3) & 3);    // stays in [0,1024)
        axg[i] = (lsl >> 2) * 32 + (lsl & 3) * 8;
    }

    f32x4 acc[4][9];
    #pragma unroll
    for (int m = 0; m < 4; ++m)
        #pragma unroll
        for (int n = 0; n < 9; ++n) acc[m][n] = 0.f;

    // ---- prologue: A(0) + B(0) ----
    #pragma unroll
    for (int i = 0; i < 2; ++i)
        lds_load16(&s_a[0][(size_t)(i * 512 + tid) * 8], wp + axg[i]);
    #pragma unroll
    for (int i = 0; i < 4; ++i)
        lds_load16(&s_b[0][(size_t)(i * 512 + tid) * 8], img + bxg[i]);
    MEMFENCE(); SB();
    asm volatile("s_waitcnt vmcnt(0)" ::: "memory");
    SB();
    __builtin_amdgcn_s_barrier();
    SB();

    for (int c = 0; c < 8; ++c) {
        #pragma unroll
        for (int k9 = 0; k9 < 9; ++k9) {
            const int s = c * 9 + k9;
            const int kh = k9 / 3, kw = k9 - 3 * kh;
            const unsigned short* sac = s_a[s & 1];
            const unsigned short* sbc = s_b[c & 1];

            // ---- staging issues ----
            if (s < 71) {
                #pragma unroll
                for (int i = 0; i < 2; ++i)
                    lds_load16(&s_a[(s + 1) & 1][(size_t)(i * 512 + tid) * 8],
                               wp + (size_t)(s + 1) * 8192 + axg[i]);
            }
            if (c < 7 && k9 >= 4 && k9 <= 7) {
                const int i = k9 - 4;
                lds_load16(&s_b[(c + 1) & 1][(size_t)(i * 512 + tid) * 8],
                           img + bxg[i] + (c + 1) * 32);
            }
            MEMFENCE(); SB();

            // ---- fragment reads (4 A + 9 B ds_read_b128) ----
            bf16x8 af[4], bf[9];
            #pragma unroll
            for (int m = 0; m < 4; ++m) {
                const int co = g * 64 + m * 16 + l15;
                af[m] = *(const bf16x8*)&sac[co * 32 + qa * 8];
            }
            #pragma unroll
            for (int n = 0; n < 9; ++n) {
                const int hr = h * 9 + n;
                const int P = (hr / 3 + kh) * 50 + (hr % 3) * 16 + l15 + kw;
                bf[n] = *(const bf16x8*)&sbc[P * 32 + ((qq ^ ((P >> 1) & 3)) << 3)];
            }
            MEMFENCE(); SB();
            __builtin_amdgcn_s_barrier();          // all waves issued
            asm volatile("s_waitcnt lgkmcnt(0)" ::: "memory");
            SB();

            // ---- 36 MFMA (intrinsic: compiler manages hazards/AGPRs) ----
            __builtin_amdgcn_s_setprio(1);
            #pragma unroll
            for (int n = 0; n < 9; ++n)
                #pragma unroll
                for (int m = 0; m < 4; ++m)
                    acc[m][n] = __builtin_amdgcn_mfma_f32_16x16x32_bf16(af[m], bf[n], acc[m][n], 0, 0, 0);
            __builtin_amdgcn_s_setprio(0);
            SB();

            // ---- drain: everything outstanding was issued this step (had
            //      the whole ~1400-cyc compute phase to land) or earlier ----
            asm volatile("s_waitcnt vmcnt(0)" ::: "memory");
            SB();
            __builtin_amdgcn_s_barrier();
            SB();
        }
    }

    // ---- epilogue ----
    if constexpr (MODE == 0) {
        const float pw = prelu_w[0];
        unsigned short* aout = (unsigned short*)outp;
        #pragma unroll
        for (int n = 0; n < 9; ++n) {
            const int hr = h * 9 + n;
            const int row_p = R0 + hr / 3 + 1;
            const int col_p = C0 + (hr % 3) * 16 + l15 + 1;
            size_t pix = ((size_t)(b * PH + row_p)) * PW + col_p;
            #pragma unroll
            for (int m = 0; m < 4; ++m) {
                const int cb = g * 64 + m * 16 + qq * 4;
                float r[4];
                #pragma unroll
                for (int j = 0; j < 4; ++j) {
                    const int ch = cb + j;
                    float s = acc[m][n][j];
                    if (ch < 86)        r[j] = s >= 0.f ? s : pw * s;
                    else if (ch < 171)  r[j] = fmaxf(s, 0.f);
                    else {
                        float e = __expf(2.f * s);
                        r[j] = 1.f - 2.f / (e + 1.f);
                    }
                }
                ushort4 o;
                o.x = f2bf(r[0]); o.y = f2bf(r[1]); o.z = f2bf(r[2]); o.w = f2bf(r[3]);
                *(ushort4*)(aout + pix * 256 + cb) = o;
            }
        }
    } else {
        float* fout = (float*)outp;
        #pragma unroll
        for (int n = 0; n < 9; ++n) {
            const int hr = h * 9 + n;
            const int row = tr * 6 + hr / 3;
            const int col = tc * 48 + (hr % 3) * 16 + l15;
            #pragma unroll
            for (int m = 0; m < 4; ++m) {
                const int cb = g * 64 + m * 16 + qq * 4;
                size_t base = ((size_t)(b * Cn + cb)) * HW + (size_t)row * Wn + col;
                #pragma unroll
                for (int j = 0; j < 4; ++j)
                    fout[base + (size_t)j * HW] = acc[m][n][j] * 0.1f + xres[base + (size_t)j * HW];
            }
        }
    }
}

extern "C" void kernel_launch(void* const* d_in, const int* in_sizes, int n_in,
                              void* d_out, int out_size, void* d_ws, size_t ws_size,
                              hipStream_t stream) {
    const float* x  = (const float*)d_in[0];
    const float* w2 = (const float*)d_in[1];
    const float* w3 = (const float*)d_in[2];
    const float* pw = (const float*)d_in[3];
    float* out = (float*)d_out;
    char* ws = (char*)d_ws;

    // ws layout: a_cl (78,675,968 B) | wp2 (1,179,648 B) | wp3 (1,179,648 B)
    // (dead tail A-prefetch reads <=8KB past wp2/wp3 - lands in wp3/slack,
    //  harmless; total 81 MB << ws)
    unsigned short* a_cl = (unsigned short*)ws;
    unsigned short* wp2  = (unsigned short*)(ws + 78675968);
    unsigned short* wp3  = (unsigned short*)(ws + 78675968 + 1179648);
    // x_pad aliases d_out (78.7 MB <= 151 MB); dead before conv<1> writes d_out.
    unsigned short* x_pad = (unsigned short*)d_out;

    zero_border_k<<<776, 256, 0, stream>>>(x_pad);
    zero_border_k<<<776, 256, 0, stream>>>(a_cl);
    pack_w_k<true ><<<2304, 256, 0, stream>>>(w2, wp2);
    pack_w_k<false><<<2304, 256, 0, stream>>>(w3, wp3);
    transform_x_k<<<dim3(3, 96, 128), 256, 0, stream>>>(x, x_pad);

    conv_k<0><<<512, 512, 0, stream>>>(x_pad, wp2, pw, nullptr, (void*)a_cl);
    conv_k<1><<<512, 512, 0, stream>>>(a_cl, wp3, nullptr, x, (void*)out);
}